// Round 5
// baseline (698.887 us; speedup 1.0000x reference)
//
#include <hip/hip_runtime.h>
#include <hip/hip_bf16.h>

#define HW 4096
#define CCH 64

typedef __attribute__((ext_vector_type(8))) short short8;
typedef __attribute__((ext_vector_type(4))) float f32x4;
typedef unsigned short ushort_t;
typedef unsigned long long u64;

__device__ __forceinline__ unsigned short f2b(float f) {
  unsigned u = __float_as_uint(f);
  return (unsigned short)((u + 0x7fff + ((u >> 16) & 1)) >> 16);  // RNE
}
__device__ __forceinline__ float b2f(ushort_t u) {
  return __uint_as_float(((unsigned)u) << 16);
}
__device__ __forceinline__ unsigned cvtpk(float lo, float hi) {
  unsigned r;
  asm volatile("v_cvt_pk_bf16_f32 %0, %1, %2" : "=v"(r) : "v"(lo), "v"(hi));
  return r;
}

// ---------------- depthwise convs (3x3 pad1 + 5x5 pad2, reflect), bf16 out ----------------
// 1024 blocks: [bc 0..255][strip 0..3], 16-row strips, 256 thr x 4 px.
__global__ void __launch_bounds__(256) k_dwconv(
    const float* __restrict__ in, const float* __restrict__ w1, const float* __restrict__ b1,
    const float* __restrict__ w2, const float* __restrict__ b2,
    ushort_t* __restrict__ x, ushort_t* __restrict__ y) {
  __shared__ float sm[20 * 68];
  const int bc = blockIdx.x >> 2;
  const int r0 = (blockIdx.x & 3) * 16;
  const int c = bc & 63;
  const float* p = in + bc * HW;
  const int tid = threadIdx.x;
  for (int idx = tid; idx < 20 * 68; idx += 256) {
    int r = r0 + idx / 68 - 2, cc = idx % 68 - 2;
    r = r < 0 ? -r : (r > 63 ? 126 - r : r);
    cc = cc < 0 ? -cc : (cc > 63 ? 126 - cc : cc);
    sm[idx] = p[r * 64 + cc];
  }
  float w1r[9], w2r[25];
  for (int i = 0; i < 9; i++) w1r[i] = w1[c * 9 + i];
  for (int i = 0; i < 25; i++) w2r[i] = w2[c * 25 + i];
  const float bb1 = b1[c], bb2 = b2[c];
  __syncthreads();
  for (int k = 0; k < 4; k++) {
    int pix = tid + k * 256;
    int i = pix >> 6, j = pix & 63;
    float a1 = bb1, a2 = bb2;
    for (int u = 0; u < 3; u++)
      for (int v = 0; v < 3; v++)
        a1 += w1r[u * 3 + v] * sm[(i + 1 + u) * 68 + (j + 1 + v)];
    for (int u = 0; u < 5; u++)
      for (int v = 0; v < 5; v++)
        a2 += w2r[u * 5 + v] * sm[(i + u) * 68 + (j + v)];
    a1 = a1 > 0.f ? a1 : 0.01f * a1;
    a2 = a2 > 0.f ? a2 : 0.01f * a2;
    x[bc * HW + (r0 + i) * 64 + j] = f2b(a1);
    y[bc * HW + (r0 + i) * 64 + j] = f2b(a2);
  }
}

// ---------------- GN stats -> per-channel scale/shift (folded gamma/beta) ----------------
__global__ void __launch_bounds__(256) k_stat(
    const ushort_t* __restrict__ xbf, const ushort_t* __restrict__ ybf,
    const float* __restrict__ gwA, const float* __restrict__ gbA,
    const float* __restrict__ gwB, const float* __restrict__ gbB,
    float* __restrict__ scale, float* __restrict__ shift) {
  const int id = blockIdx.x;          // [t][b][g]
  const int t = id >> 6, b = (id >> 4) & 3, g = id & 15;
  const ushort_t* src = (t ? ybf : xbf) + (b * CCH + g * 4) * HW;
  const int tid = threadIdx.x;
  float s = 0.f, ss = 0.f;
  for (int k = 0; k < 8; k++) {
    const short8 v = *(const short8*)(src + (tid + k * 256) * 8);
    for (int j = 0; j < 8; j++) {
      float f = b2f((ushort_t)v[j]);
      s += f; ss += f * f;
    }
  }
  for (int off = 1; off < 64; off <<= 1) {
    s += __shfl_xor(s, off);
    ss += __shfl_xor(ss, off);
  }
  __shared__ float rs[4], rss[4];
  if ((tid & 63) == 0) { rs[tid >> 6] = s; rss[tid >> 6] = ss; }
  __syncthreads();
  if (tid < 4) {
    s = rs[0] + rs[1] + rs[2] + rs[3];
    ss = rss[0] + rss[1] + rss[2] + rss[3];
    const float mu = s * (1.f / 16384.f);
    const float var = ss * (1.f / 16384.f) - mu * mu;
    const float rsig = rsqrtf(var + 1e-5f);
    const int ch = g * 4 + tid;
    const float gwv = (t ? gwB : gwA)[ch];
    const float a = rsig * gwv;
    scale[t * 256 + b * 64 + ch] = a;
    shift[t * 256 + b * 64 + ch] = (t ? gbB : gbA)[ch] - mu * a;
  }
}

// ---------------- qkv projection (normalize inline): Qt,Kt [h][pix][64], V [h][64][pix] ----
__global__ void __launch_bounds__(256) k_qkv(
    const ushort_t* __restrict__ xbf, const ushort_t* __restrict__ ybf,
    const float* __restrict__ scale, const float* __restrict__ shift,
    const float* __restrict__ wA, const float* __restrict__ wB,
    ushort_t* __restrict__ Qt, ushort_t* __restrict__ Kt, ushort_t* __restrict__ Vv) {
  const int id = blockIdx.x * 256 + threadIdx.x;
  const int pg = id & 1023;
  const int chunk = (id >> 10) % 24;
  const int h = id / (1024 * 24);     // 0..7 = b*2+br
  const int b = h >> 1, br = h & 1;
  const ushort_t* X = (br ? ybf : xbf) + b * (CCH * HW);
  const float* W = br ? wB : wA;
  const int sidx = br * 256 + b * 64;
  const int pix0 = pg * 4;
  const int r0 = chunk * 8;
  float acc[8][4];
  for (int r = 0; r < 8; r++) for (int p = 0; p < 4; p++) acc[r][p] = 0.f;
  for (int cc = 0; cc < 64; cc++) {
    const float sc = scale[sidx + cc], sh = shift[sidx + cc];
    const u64 raw = *(const u64*)(X + cc * HW + pix0);
    f32x4 xv;
    for (int p = 0; p < 4; p++)
      xv[p] = b2f((ushort_t)(raw >> (16 * p))) * sc + sh;
    for (int r = 0; r < 8; r++) {
      float wv = W[(r0 + r) * 64 + cc];
      for (int p = 0; p < 4; p++) acc[r][p] += wv * xv[p];
    }
  }
  if (chunk < 16) {                    // Q or K rows -> transposed [pix][d]
    ushort_t* dst = chunk < 8 ? Qt : Kt;
    const int d0 = (chunk & 7) * 8;
    for (int p = 0; p < 4; p++) {
      short8 v;
      for (int r = 0; r < 8; r++) v[r] = (short)f2b(acc[r][p]);
      *(short8*)(dst + ((h * HW + pix0 + p) << 6) + d0) = v;
    }
  } else {                             // V rows -> natural [d][pix]
    const int d0 = (chunk - 16) * 8;
    for (int r = 0; r < 8; r++) {
      ushort_t tmp[4];
      for (int p = 0; p < 4; p++) tmp[p] = f2b(acc[r][p]);
      *(u64*)(Vv + (h * CCH + d0 + r) * HW + pix0) = *(const u64*)tmp;
    }
  }
}

// ---------------- flash cross-attention, in-block split-K x4, fused epilogue ----------------
// 512 blocks x 1024 thr (16 waves). wave w: qsub=w&3 (16 queries), slice=w>>2 (1024 keys).
__global__ void __launch_bounds__(1024, 8) k_attn(
    const ushort_t* __restrict__ Qt, const ushort_t* __restrict__ Kt,
    const ushort_t* __restrict__ Vv,
    const float* __restrict__ oAw, const float* __restrict__ oAb,
    const float* __restrict__ oBw, const float* __restrict__ oBb,
    const ushort_t* __restrict__ xbf, const ushort_t* __restrict__ ybf,
    const float* __restrict__ scale, const float* __restrict__ shift,
    float* __restrict__ out) {
  __shared__ char plds[16][2048];      // 2KB/wave P^T staging, XOR-swizzled
  __shared__ float smO[64][64];        // combined attn output [d][qcol]
  __shared__ float cm[16][16], cl[16][16];
  const int h = blockIdx.x >> 6;
  const int qt = blockIdx.x & 63;
  const int b = h >> 1, br = h & 1;
  const int qh = b * 2 + (1 - br);
  const int tid = threadIdx.x;
  const int lane = tid & 63;
  const int wave = tid >> 6;
  const int qsub = wave & 3, slice = wave >> 2;
  const int q = lane & 15, g = lane >> 4;
  const int qbase = qt * 64 + qsub * 16;

  for (int i = tid; i < 4096; i += 1024) ((float*)smO)[i] = 0.f;

  const ushort_t* Qp = Qt + ((qh * HW + qbase + q) << 6);
  const short8 qf0 = *(const short8*)(Qp + g * 8);        // B-frag: Q[d=g*8+j][q]
  const short8 qf1 = *(const short8*)(Qp + 32 + g * 8);

  const ushort_t* Kp = Kt + (h * HW << 6);
  const ushort_t* Vp = Vv + h * (CCH * HW);

  float m_run = -1e30f, l_run = 0.f;
  f32x4 o[4] = {};
  char* wp = plds[wave] + (q << 7);
  const int sw = (q & 7) << 4;

  for (int it = 0; it < 16; it++) {
    const int kt = slice * 16 + it;
    const ushort_t* Kb = Kp + (kt * 64 << 6);
    short8 ka[4][2], va[4][2];
    for (int c = 0; c < 4; c++)
      for (int s = 0; s < 2; s++)
        ka[c][s] = *(const short8*)(Kb + ((c * 16 + q) << 6) + s * 32 + g * 8);
    for (int cd = 0; cd < 4; cd++)
      for (int s = 0; s < 2; s++)
        va[cd][s] = *(const short8*)(Vp + (cd * 16 + q) * HW + kt * 64 + s * 32 + g * 8);

    // S^T[k_local, q] = sum_d K[d,k] Q[d,q]   (swapped operands -> q is lane-local column)
    f32x4 sa[4];
    for (int c = 0; c < 4; c++) {
      f32x4 zz = {0.f, 0.f, 0.f, 0.f};
      zz = __builtin_amdgcn_mfma_f32_16x16x32_bf16(ka[c][0], qf0, zz, 0, 0, 0);
      sa[c] = __builtin_amdgcn_mfma_f32_16x16x32_bf16(ka[c][1], qf1, zz, 0, 0, 0);
    }
    const float sc = 0.125f * 1.44269504f;  // (1/sqrt(C)) * log2(e)
    float z[4][4];
    float mloc = -1e30f;
    for (int c = 0; c < 4; c++)
      for (int i = 0; i < 4; i++) {
        z[c][i] = sa[c][i] * sc;
        mloc = fmaxf(mloc, z[c][i]);
      }
    mloc = fmaxf(mloc, __shfl_xor(mloc, 16));
    mloc = fmaxf(mloc, __shfl_xor(mloc, 32));
    // defer-max (T13): only rescale when tile max grows past m_run + 8
    if (!__all(mloc <= m_run + 8.f)) {
      const float mnew = fmaxf(m_run, mloc);
      const float alpha = exp2f(m_run - mnew);
      l_run *= alpha;
      for (int cd = 0; cd < 4; cd++)
        for (int i = 0; i < 4; i++) o[cd][i] *= alpha;
      m_run = mnew;
    }
    float psum = 0.f;
    u64 pk[4];
    for (int c = 0; c < 4; c++) {
      float p0 = exp2f(z[c][0] - m_run), p1 = exp2f(z[c][1] - m_run);
      float p2 = exp2f(z[c][2] - m_run), p3 = exp2f(z[c][3] - m_run);
      psum += p0 + p1 + p2 + p3;
      pk[c] = (u64)cvtpk(p0, p1) | ((u64)cvtpk(p2, p3) << 32);
    }
    psum += __shfl_xor(psum, 16);
    psum += __shfl_xor(psum, 32);
    l_run += psum;
    // stage P^T (keys c*16+4g+i at column q) into wave-local LDS, XOR-swizzled
    for (int c = 0; c < 4; c++)
      *(u64*)(wp + (((c << 5) | (g << 3)) ^ sw)) = pk[c];
    asm volatile("s_waitcnt lgkmcnt(0)" ::: "memory");
    __builtin_amdgcn_sched_barrier(0);
    const short8 pb0 = *(const short8*)(wp + ((g << 4) ^ sw));
    const short8 pb1 = *(const short8*)(wp + ((64 | (g << 4)) ^ sw));
    for (int cd = 0; cd < 4; cd++) {
      o[cd] = __builtin_amdgcn_mfma_f32_16x16x32_bf16(va[cd][0], pb0, o[cd], 0, 0, 0);
      o[cd] = __builtin_amdgcn_mfma_f32_16x16x32_bf16(va[cd][1], pb1, o[cd], 0, 0, 0);
    }
    asm volatile("s_waitcnt lgkmcnt(0)" ::: "memory");
    __builtin_amdgcn_sched_barrier(0);
  }

  // ---- in-block split-K combine ----
  if (lane < 16) { cm[wave][lane] = m_run; cl[wave][lane] = l_run; }
  __syncthreads();
  float M = -1e30f;
  float ms[4], ls[4];
  for (int s = 0; s < 4; s++) {
    ms[s] = cm[s * 4 + qsub][q];
    ls[s] = cl[s * 4 + qsub][q];
    M = fmaxf(M, ms[s]);
  }
  float L = 0.f;
  for (int s = 0; s < 4; s++) L += exp2f(ms[s] - M) * ls[s];
  const float f = exp2f(m_run - M) / L;
  for (int cd = 0; cd < 4; cd++)
    for (int i = 0; i < 4; i++)
      atomicAdd(&smO[cd * 16 + g * 4 + i][qsub * 16 + q], o[cd][i] * f);
  __syncthreads();

  // ---- fused epilogue: out-proj (4 ch per wave) + bias + residual(GN inline) ----
  const float* W    = br ? oBw : oAw;
  const float* bias = br ? oBb : oAb;
  const ushort_t* xR = (br ? ybf : xbf) + b * (CCH * HW);
  const int sidx = br * 256 + b * 64;
  const int och0 = wave * 4;
  const int pix = qt * 64 + lane;

  float acc[4];
  for (int oi = 0; oi < 4; oi++) acc[oi] = bias[och0 + oi];
  for (int c4 = 0; c4 < 16; c4++) {
    f32x4 Lv = {smO[c4 * 4 + 0][lane], smO[c4 * 4 + 1][lane],
                smO[c4 * 4 + 2][lane], smO[c4 * 4 + 3][lane]};
    for (int oi = 0; oi < 4; oi++) {
      const f32x4 wv = *(const f32x4*)(W + (och0 + oi) * 64 + c4 * 4);
      acc[oi] += wv[0] * Lv[0] + wv[1] * Lv[1] + wv[2] * Lv[2] + wv[3] * Lv[3];
    }
  }
  for (int oi = 0; oi < 4; oi++) {
    const int ch = och0 + oi;
    const float xn = b2f(xR[ch * HW + pix]) * scale[sidx + ch] + shift[sidx + ch];
    out[(b * 128 + br * 64 + ch) * HW + pix] = acc[oi] + xn;
  }
}

extern "C" void kernel_launch(void* const* d_in, const int* in_sizes, int n_in,
                              void* d_out, int out_size, void* d_ws, size_t ws_size,
                              hipStream_t stream) {
  const float* in   = (const float*)d_in[0];
  const float* dw1w = (const float*)d_in[1];
  const float* dw1b = (const float*)d_in[2];
  const float* dw2w = (const float*)d_in[3];
  const float* dw2b = (const float*)d_in[4];
  const float* gnAw = (const float*)d_in[5];
  const float* gnAb = (const float*)d_in[6];
  const float* gnBw = (const float*)d_in[7];
  const float* gnBb = (const float*)d_in[8];
  const float* qAw  = (const float*)d_in[9];
  const float* qBw  = (const float*)d_in[10];
  const float* oAw  = (const float*)d_in[11];
  const float* oAb  = (const float*)d_in[12];
  const float* oBw  = (const float*)d_in[13];
  const float* oBb  = (const float*)d_in[14];
  float* out = (float*)d_out;

  // compact workspace layout: 16 MB + 4 KB
  char* ws = (char*)d_ws;
  ushort_t* xbf = (ushort_t*)ws;             // [4][64][4096] bf16 conv out A
  ushort_t* ybf = xbf + 1048576;             // [4][64][4096] bf16 conv out B
  ushort_t* Qt  = ybf + 1048576;             // [8][4096][64] bf16
  ushort_t* Kt  = Qt + 2097152;              // [8][4096][64] bf16
  ushort_t* Vv  = Kt + 2097152;              // [8][64][4096] bf16
  float* scale  = (float*)(Vv + 2097152);    // [2][4][64]
  float* shift  = scale + 512;               // [2][4][64]

  k_dwconv<<<1024, 256, 0, stream>>>(in, dw1w, dw1b, dw2w, dw2b, xbf, ybf);
  k_stat<<<128, 256, 0, stream>>>(xbf, ybf, gnAw, gnAb, gnBw, gnBb, scale, shift);
  k_qkv<<<768, 256, 0, stream>>>(xbf, ybf, scale, shift, qAw, qBw, Qt, Kt, Vv);
  k_attn<<<512, 1024, 0, stream>>>(Qt, Kt, Vv, oAw, oAb, oBw, oBb,
                                   xbf, ybf, scale, shift, out);
}

// Round 6
// 407.781 us; speedup vs baseline: 1.7139x; 1.7139x over previous
//
#include <hip/hip_runtime.h>
#include <hip/hip_bf16.h>

#define HW 4096
#define CCH 64

typedef __attribute__((ext_vector_type(8))) short short8;
typedef __attribute__((ext_vector_type(4))) float f32x4;
typedef unsigned short ushort_t;
typedef unsigned long long u64;

__device__ __forceinline__ unsigned short f2b(float f) {
  unsigned u = __float_as_uint(f);
  return (unsigned short)((u + 0x7fff + ((u >> 16) & 1)) >> 16);  // RNE
}
__device__ __forceinline__ float b2f(ushort_t u) {
  return __uint_as_float(((unsigned)u) << 16);
}
__device__ __forceinline__ unsigned cvtpk(float lo, float hi) {
  unsigned r;
  asm volatile("v_cvt_pk_bf16_f32 %0, %1, %2" : "=v"(r) : "v"(lo), "v"(hi));
  return r;
}

// ---------------- depthwise convs (3x3 pad1 + 5x5 pad2, reflect), bf16 out ----------------
// 1024 blocks: [bc 0..255][strip 0..3], 16-row strips, 256 thr x 4 px.
__global__ void __launch_bounds__(256) k_dwconv(
    const float* __restrict__ in, const float* __restrict__ w1, const float* __restrict__ b1,
    const float* __restrict__ w2, const float* __restrict__ b2,
    ushort_t* __restrict__ x, ushort_t* __restrict__ y) {
  __shared__ float sm[20 * 68];
  const int bc = blockIdx.x >> 2;
  const int r0 = (blockIdx.x & 3) * 16;
  const int c = bc & 63;
  const float* p = in + bc * HW;
  const int tid = threadIdx.x;
  for (int idx = tid; idx < 20 * 68; idx += 256) {
    int r = r0 + idx / 68 - 2, cc = idx % 68 - 2;
    r = r < 0 ? -r : (r > 63 ? 126 - r : r);
    cc = cc < 0 ? -cc : (cc > 63 ? 126 - cc : cc);
    sm[idx] = p[r * 64 + cc];
  }
  float w1r[9], w2r[25];
  for (int i = 0; i < 9; i++) w1r[i] = w1[c * 9 + i];
  for (int i = 0; i < 25; i++) w2r[i] = w2[c * 25 + i];
  const float bb1 = b1[c], bb2 = b2[c];
  __syncthreads();
  for (int k = 0; k < 4; k++) {
    int pix = tid + k * 256;
    int i = pix >> 6, j = pix & 63;
    float a1 = bb1, a2 = bb2;
    for (int u = 0; u < 3; u++)
      for (int v = 0; v < 3; v++)
        a1 += w1r[u * 3 + v] * sm[(i + 1 + u) * 68 + (j + 1 + v)];
    for (int u = 0; u < 5; u++)
      for (int v = 0; v < 5; v++)
        a2 += w2r[u * 5 + v] * sm[(i + u) * 68 + (j + v)];
    a1 = a1 > 0.f ? a1 : 0.01f * a1;
    a2 = a2 > 0.f ? a2 : 0.01f * a2;
    x[bc * HW + (r0 + i) * 64 + j] = f2b(a1);
    y[bc * HW + (r0 + i) * 64 + j] = f2b(a2);
  }
}

// ---------------- GN stats -> per-channel scale/shift (folded gamma/beta) ----------------
__global__ void __launch_bounds__(256) k_stat(
    const ushort_t* __restrict__ xbf, const ushort_t* __restrict__ ybf,
    const float* __restrict__ gwA, const float* __restrict__ gbA,
    const float* __restrict__ gwB, const float* __restrict__ gbB,
    float* __restrict__ scale, float* __restrict__ shift) {
  const int id = blockIdx.x;          // [t][b][g]
  const int t = id >> 6, b = (id >> 4) & 3, g = id & 15;
  const ushort_t* src = (t ? ybf : xbf) + (b * CCH + g * 4) * HW;
  const int tid = threadIdx.x;
  float s = 0.f, ss = 0.f;
  for (int k = 0; k < 8; k++) {
    const short8 v = *(const short8*)(src + (tid + k * 256) * 8);
    for (int j = 0; j < 8; j++) {
      float f = b2f((ushort_t)v[j]);
      s += f; ss += f * f;
    }
  }
  for (int off = 1; off < 64; off <<= 1) {
    s += __shfl_xor(s, off);
    ss += __shfl_xor(ss, off);
  }
  __shared__ float rs[4], rss[4];
  if ((tid & 63) == 0) { rs[tid >> 6] = s; rss[tid >> 6] = ss; }
  __syncthreads();
  if (tid < 4) {
    s = rs[0] + rs[1] + rs[2] + rs[3];
    ss = rss[0] + rss[1] + rss[2] + rss[3];
    const float mu = s * (1.f / 16384.f);
    const float var = ss * (1.f / 16384.f) - mu * mu;
    const float rsig = rsqrtf(var + 1e-5f);
    const int ch = g * 4 + tid;
    const float gwv = (t ? gwB : gwA)[ch];
    const float a = rsig * gwv;
    scale[t * 256 + b * 64 + ch] = a;
    shift[t * 256 + b * 64 + ch] = (t ? gbB : gbA)[ch] - mu * a;
  }
}

// ---------------- qkv projection (normalize inline): Qt,Kt [h][pix][64], V [h][64][pix] ----
__global__ void __launch_bounds__(256) k_qkv(
    const ushort_t* __restrict__ xbf, const ushort_t* __restrict__ ybf,
    const float* __restrict__ scale, const float* __restrict__ shift,
    const float* __restrict__ wA, const float* __restrict__ wB,
    ushort_t* __restrict__ Qt, ushort_t* __restrict__ Kt, ushort_t* __restrict__ Vv) {
  const int id = blockIdx.x * 256 + threadIdx.x;
  const int pg = id & 1023;
  const int chunk = (id >> 10) % 24;
  const int h = id / (1024 * 24);     // 0..7 = b*2+br
  const int b = h >> 1, br = h & 1;
  const ushort_t* X = (br ? ybf : xbf) + b * (CCH * HW);
  const float* W = br ? wB : wA;
  const int sidx = br * 256 + b * 64;
  const int pix0 = pg * 4;
  const int r0 = chunk * 8;
  float acc[8][4];
  for (int r = 0; r < 8; r++) for (int p = 0; p < 4; p++) acc[r][p] = 0.f;
  for (int cc = 0; cc < 64; cc++) {
    const float sc = scale[sidx + cc], sh = shift[sidx + cc];
    const u64 raw = *(const u64*)(X + cc * HW + pix0);
    f32x4 xv;
    for (int p = 0; p < 4; p++)
      xv[p] = b2f((ushort_t)(raw >> (16 * p))) * sc + sh;
    for (int r = 0; r < 8; r++) {
      float wv = W[(r0 + r) * 64 + cc];
      for (int p = 0; p < 4; p++) acc[r][p] += wv * xv[p];
    }
  }
  if (chunk < 16) {                    // Q or K rows -> transposed [pix][d]
    ushort_t* dst = chunk < 8 ? Qt : Kt;
    const int d0 = (chunk & 7) * 8;
    for (int p = 0; p < 4; p++) {
      short8 v;
      for (int r = 0; r < 8; r++) v[r] = (short)f2b(acc[r][p]);
      *(short8*)(dst + ((h * HW + pix0 + p) << 6) + d0) = v;
    }
  } else {                             // V rows -> natural [d][pix]
    const int d0 = (chunk - 16) * 8;
    for (int r = 0; r < 8; r++) {
      ushort_t tmp[4];
      for (int p = 0; p < 4; p++) tmp[p] = f2b(acc[r][p]);
      *(u64*)(Vv + (h * CCH + d0 + r) * HW + pix0) = *(const u64*)tmp;
    }
  }
}

// ---------------- flash cross-attention, in-block split-K x4, fused epilogue ----------------
// 1024 blocks x 512 thr (8 waves). wave w: qsub=w&1 (16 queries), slice=w>>1 (1024 keys).
// Block covers 32 queries x all 4096 keys. VGPR cap 128 (2 blocks/CU, 16 waves/CU).
__global__ void __launch_bounds__(512, 4) k_attn(
    const ushort_t* __restrict__ Qt, const ushort_t* __restrict__ Kt,
    const ushort_t* __restrict__ Vv,
    const float* __restrict__ oAw, const float* __restrict__ oAb,
    const float* __restrict__ oBw, const float* __restrict__ oBb,
    const ushort_t* __restrict__ xbf, const ushort_t* __restrict__ ybf,
    const float* __restrict__ scale, const float* __restrict__ shift,
    float* __restrict__ out) {
  __shared__ char plds[8][2048];       // 2KB/wave P^T staging, XOR-swizzled
  __shared__ float smO[64][32];        // combined attn output [d][qcol], 8KB
  __shared__ float cm[8][16], cl[8][16];
  const int h = blockIdx.x >> 7;       // 8 heads
  const int qt = blockIdx.x & 127;     // 128 q-tiles of 32
  const int b = h >> 1, br = h & 1;
  const int qh = b * 2 + (1 - br);
  const int tid = threadIdx.x;
  const int lane = tid & 63;
  const int wave = tid >> 6;
  const int qsub = wave & 1, slice = wave >> 1;
  const int q = lane & 15, g = lane >> 4;
  const int qbase = qt * 32 + qsub * 16;

  for (int i = tid; i < 2048; i += 512) ((float*)smO)[i] = 0.f;

  const ushort_t* Qp = Qt + ((qh * HW + qbase + q) << 6);
  const short8 qf0 = *(const short8*)(Qp + g * 8);        // B-frag: Q[d=g*8+j][q]
  const short8 qf1 = *(const short8*)(Qp + 32 + g * 8);

  const ushort_t* Kp = Kt + (h * HW << 6);
  const ushort_t* Vp = Vv + h * (CCH * HW);

  float m_run = -1e30f, l_run = 0.f;
  f32x4 o[4] = {};
  char* wp = plds[wave] + (q << 7);
  const int sw = (q & 7) << 4;

  for (int it = 0; it < 16; it++) {
    const int kt = slice * 16 + it;
    const ushort_t* Kb = Kp + (kt * 64 << 6);
    short8 ka[4][2], va[4][2];
    for (int c = 0; c < 4; c++)
      for (int s = 0; s < 2; s++)
        ka[c][s] = *(const short8*)(Kb + ((c * 16 + q) << 6) + s * 32 + g * 8);
    for (int cd = 0; cd < 4; cd++)
      for (int s = 0; s < 2; s++)
        va[cd][s] = *(const short8*)(Vp + (cd * 16 + q) * HW + kt * 64 + s * 32 + g * 8);

    // S^T[k_local, q] = sum_d K[d,k] Q[d,q]   (swapped operands -> q is lane-local column)
    f32x4 sa[4];
    for (int c = 0; c < 4; c++) {
      f32x4 zz = {0.f, 0.f, 0.f, 0.f};
      zz = __builtin_amdgcn_mfma_f32_16x16x32_bf16(ka[c][0], qf0, zz, 0, 0, 0);
      sa[c] = __builtin_amdgcn_mfma_f32_16x16x32_bf16(ka[c][1], qf1, zz, 0, 0, 0);
    }
    const float sc = 0.125f * 1.44269504f;  // (1/sqrt(C)) * log2(e)
    float z[4][4];
    float mloc = -1e30f;
    for (int c = 0; c < 4; c++)
      for (int i = 0; i < 4; i++) {
        z[c][i] = sa[c][i] * sc;
        mloc = fmaxf(mloc, z[c][i]);
      }
    mloc = fmaxf(mloc, __shfl_xor(mloc, 16));
    mloc = fmaxf(mloc, __shfl_xor(mloc, 32));
    // defer-max (T13): only rescale when tile max grows past m_run + 8
    if (!__all(mloc <= m_run + 8.f)) {
      const float mnew = fmaxf(m_run, mloc);
      const float alpha = exp2f(m_run - mnew);
      l_run *= alpha;
      for (int cd = 0; cd < 4; cd++)
        for (int i = 0; i < 4; i++) o[cd][i] *= alpha;
      m_run = mnew;
    }
    float psum = 0.f;
    u64 pk[4];
    for (int c = 0; c < 4; c++) {
      float p0 = exp2f(z[c][0] - m_run), p1 = exp2f(z[c][1] - m_run);
      float p2 = exp2f(z[c][2] - m_run), p3 = exp2f(z[c][3] - m_run);
      psum += p0 + p1 + p2 + p3;
      pk[c] = (u64)cvtpk(p0, p1) | ((u64)cvtpk(p2, p3) << 32);
    }
    psum += __shfl_xor(psum, 16);
    psum += __shfl_xor(psum, 32);
    l_run += psum;
    // stage P^T (keys c*16+4g+i at column q) into wave-local LDS, XOR-swizzled
    for (int c = 0; c < 4; c++)
      *(u64*)(wp + (((c << 5) | (g << 3)) ^ sw)) = pk[c];
    asm volatile("s_waitcnt lgkmcnt(0)" ::: "memory");
    __builtin_amdgcn_sched_barrier(0);
    const short8 pb0 = *(const short8*)(wp + ((g << 4) ^ sw));
    const short8 pb1 = *(const short8*)(wp + ((64 | (g << 4)) ^ sw));
    for (int cd = 0; cd < 4; cd++) {
      o[cd] = __builtin_amdgcn_mfma_f32_16x16x32_bf16(va[cd][0], pb0, o[cd], 0, 0, 0);
      o[cd] = __builtin_amdgcn_mfma_f32_16x16x32_bf16(va[cd][1], pb1, o[cd], 0, 0, 0);
    }
    // (no tail pin: let next-iter loads interleave with PV)
  }

  // ---- in-block split-K combine ----
  if (lane < 16) { cm[wave][lane] = m_run; cl[wave][lane] = l_run; }
  __syncthreads();
  float M = -1e30f;
  float ms[4], ls[4];
  for (int s = 0; s < 4; s++) {
    ms[s] = cm[s * 2 + qsub][q];
    ls[s] = cl[s * 2 + qsub][q];
    M = fmaxf(M, ms[s]);
  }
  float L = 0.f;
  for (int s = 0; s < 4; s++) L += exp2f(ms[s] - M) * ls[s];
  const float f = exp2f(m_run - M) / L;
  for (int cd = 0; cd < 4; cd++)
    for (int i = 0; i < 4; i++)
      atomicAdd(&smO[cd * 16 + g * 4 + i][qsub * 16 + q], o[cd][i] * f);
  __syncthreads();

  // ---- fused epilogue: out-proj (8 ch per wave, split over lane-halves) ----
  const float* W    = br ? oBw : oAw;
  const float* bias = br ? oBb : oAb;
  const ushort_t* xR = (br ? ybf : xbf) + b * (CCH * HW);
  const int sidx = br * 256 + b * 64;
  const int pixL = lane & 31;
  const int och0 = wave * 8 + (lane >> 5) * 4;
  const int pix = qt * 32 + pixL;

  float acc[4];
  for (int oi = 0; oi < 4; oi++) acc[oi] = bias[och0 + oi];
  for (int c4 = 0; c4 < 16; c4++) {
    f32x4 Lv = {smO[c4 * 4 + 0][pixL], smO[c4 * 4 + 1][pixL],
                smO[c4 * 4 + 2][pixL], smO[c4 * 4 + 3][pixL]};
    for (int oi = 0; oi < 4; oi++) {
      const f32x4 wv = *(const f32x4*)(W + (och0 + oi) * 64 + c4 * 4);
      acc[oi] += wv[0] * Lv[0] + wv[1] * Lv[1] + wv[2] * Lv[2] + wv[3] * Lv[3];
    }
  }
  for (int oi = 0; oi < 4; oi++) {
    const int ch = och0 + oi;
    const float xn = b2f(xR[ch * HW + pix]) * scale[sidx + ch] + shift[sidx + ch];
    out[(b * 128 + br * 64 + ch) * HW + pix] = acc[oi] + xn;
  }
}

extern "C" void kernel_launch(void* const* d_in, const int* in_sizes, int n_in,
                              void* d_out, int out_size, void* d_ws, size_t ws_size,
                              hipStream_t stream) {
  const float* in   = (const float*)d_in[0];
  const float* dw1w = (const float*)d_in[1];
  const float* dw1b = (const float*)d_in[2];
  const float* dw2w = (const float*)d_in[3];
  const float* dw2b = (const float*)d_in[4];
  const float* gnAw = (const float*)d_in[5];
  const float* gnAb = (const float*)d_in[6];
  const float* gnBw = (const float*)d_in[7];
  const float* gnBb = (const float*)d_in[8];
  const float* qAw  = (const float*)d_in[9];
  const float* qBw  = (const float*)d_in[10];
  const float* oAw  = (const float*)d_in[11];
  const float* oAb  = (const float*)d_in[12];
  const float* oBw  = (const float*)d_in[13];
  const float* oBb  = (const float*)d_in[14];
  float* out = (float*)d_out;

  // compact workspace layout: 16 MB + 4 KB
  char* ws = (char*)d_ws;
  ushort_t* xbf = (ushort_t*)ws;             // [4][64][4096] bf16 conv out A
  ushort_t* ybf = xbf + 1048576;             // [4][64][4096] bf16 conv out B
  ushort_t* Qt  = ybf + 1048576;             // [8][4096][64] bf16
  ushort_t* Kt  = Qt + 2097152;              // [8][4096][64] bf16
  ushort_t* Vv  = Kt + 2097152;              // [8][64][4096] bf16
  float* scale  = (float*)(Vv + 2097152);    // [2][4][64]
  float* shift  = scale + 512;               // [2][4][64]

  k_dwconv<<<1024, 256, 0, stream>>>(in, dw1w, dw1b, dw2w, dw2b, xbf, ybf);
  k_stat<<<128, 256, 0, stream>>>(xbf, ybf, gnAw, gnAb, gnBw, gnBb, scale, shift);
  k_qkv<<<768, 256, 0, stream>>>(xbf, ybf, scale, shift, qAw, qBw, Qt, Kt, Vv);
  k_attn<<<1024, 512, 0, stream>>>(Qt, Kt, Vv, oAw, oAb, oBw, oBb,
                                   xbf, ybf, scale, shift, out);
}

// Round 7
// 228.246 us; speedup vs baseline: 3.0620x; 1.7866x over previous
//
#include <hip/hip_runtime.h>
#include <hip/hip_bf16.h>

#define HW 4096
#define CCH 64

typedef __attribute__((ext_vector_type(8))) short short8;
typedef __attribute__((ext_vector_type(4))) float f32x4;
typedef unsigned short ushort_t;
typedef unsigned long long u64;

__device__ __forceinline__ unsigned short f2b(float f) {
  unsigned u = __float_as_uint(f);
  return (unsigned short)((u + 0x7fff + ((u >> 16) & 1)) >> 16);  // RNE
}
__device__ __forceinline__ float b2f(ushort_t u) {
  return __uint_as_float(((unsigned)u) << 16);
}
__device__ __forceinline__ unsigned cvtpk(float lo, float hi) {
  unsigned r;
  asm volatile("v_cvt_pk_bf16_f32 %0, %1, %2" : "=v"(r) : "v"(lo), "v"(hi));
  return r;
}
__device__ __forceinline__ void gload16(const void* g, void* l) {
  __builtin_amdgcn_global_load_lds(
      (const __attribute__((address_space(1))) unsigned int*)g,
      (__attribute__((address_space(3))) unsigned int*)l, 16, 0, 0);
}

// ---------------- depthwise convs (3x3 pad1 + 5x5 pad2, reflect), bf16 out ----------------
__global__ void __launch_bounds__(256) k_dwconv(
    const float* __restrict__ in, const float* __restrict__ w1, const float* __restrict__ b1,
    const float* __restrict__ w2, const float* __restrict__ b2,
    ushort_t* __restrict__ x, ushort_t* __restrict__ y) {
  __shared__ float sm[20 * 68];
  const int bc = blockIdx.x >> 2;
  const int r0 = (blockIdx.x & 3) * 16;
  const int c = bc & 63;
  const float* p = in + bc * HW;
  const int tid = threadIdx.x;
  for (int idx = tid; idx < 20 * 68; idx += 256) {
    int r = r0 + idx / 68 - 2, cc = idx % 68 - 2;
    r = r < 0 ? -r : (r > 63 ? 126 - r : r);
    cc = cc < 0 ? -cc : (cc > 63 ? 126 - cc : cc);
    sm[idx] = p[r * 64 + cc];
  }
  float w1r[9], w2r[25];
  for (int i = 0; i < 9; i++) w1r[i] = w1[c * 9 + i];
  for (int i = 0; i < 25; i++) w2r[i] = w2[c * 25 + i];
  const float bb1 = b1[c], bb2 = b2[c];
  __syncthreads();
  for (int k = 0; k < 4; k++) {
    int pix = tid + k * 256;
    int i = pix >> 6, j = pix & 63;
    float a1 = bb1, a2 = bb2;
    for (int u = 0; u < 3; u++)
      for (int v = 0; v < 3; v++)
        a1 += w1r[u * 3 + v] * sm[(i + 1 + u) * 68 + (j + 1 + v)];
    for (int u = 0; u < 5; u++)
      for (int v = 0; v < 5; v++)
        a2 += w2r[u * 5 + v] * sm[(i + u) * 68 + (j + v)];
    a1 = a1 > 0.f ? a1 : 0.01f * a1;
    a2 = a2 > 0.f ? a2 : 0.01f * a2;
    x[bc * HW + (r0 + i) * 64 + j] = f2b(a1);
    y[bc * HW + (r0 + i) * 64 + j] = f2b(a2);
  }
}

// ---------------- GN stats -> per-channel scale/shift (folded gamma/beta) ----------------
__global__ void __launch_bounds__(256) k_stat(
    const ushort_t* __restrict__ xbf, const ushort_t* __restrict__ ybf,
    const float* __restrict__ gwA, const float* __restrict__ gbA,
    const float* __restrict__ gwB, const float* __restrict__ gbB,
    float* __restrict__ scale, float* __restrict__ shift) {
  const int id = blockIdx.x;          // [t][b][g]
  const int t = id >> 6, b = (id >> 4) & 3, g = id & 15;
  const ushort_t* src = (t ? ybf : xbf) + (b * CCH + g * 4) * HW;
  const int tid = threadIdx.x;
  float s = 0.f, ss = 0.f;
  for (int k = 0; k < 8; k++) {
    const short8 v = *(const short8*)(src + (tid + k * 256) * 8);
    for (int j = 0; j < 8; j++) {
      float f = b2f((ushort_t)v[j]);
      s += f; ss += f * f;
    }
  }
  for (int off = 1; off < 64; off <<= 1) {
    s += __shfl_xor(s, off);
    ss += __shfl_xor(ss, off);
  }
  __shared__ float rs[4], rss[4];
  if ((tid & 63) == 0) { rs[tid >> 6] = s; rss[tid >> 6] = ss; }
  __syncthreads();
  if (tid < 4) {
    s = rs[0] + rs[1] + rs[2] + rs[3];
    ss = rss[0] + rss[1] + rss[2] + rss[3];
    const float mu = s * (1.f / 16384.f);
    const float var = ss * (1.f / 16384.f) - mu * mu;
    const float rsig = rsqrtf(var + 1e-5f);
    const int ch = g * 4 + tid;
    const float gwv = (t ? gwB : gwA)[ch];
    const float a = rsig * gwv;
    scale[t * 256 + b * 64 + ch] = a;
    shift[t * 256 + b * 64 + ch] = (t ? gbB : gbA)[ch] - mu * a;
  }
}

// ---------------- qkv projection (normalize inline): Qt,Kt [h][pix][64], V [h][64][pix] ----
__global__ void __launch_bounds__(256) k_qkv(
    const ushort_t* __restrict__ xbf, const ushort_t* __restrict__ ybf,
    const float* __restrict__ scale, const float* __restrict__ shift,
    const float* __restrict__ wA, const float* __restrict__ wB,
    ushort_t* __restrict__ Qt, ushort_t* __restrict__ Kt, ushort_t* __restrict__ Vv) {
  const int id = blockIdx.x * 256 + threadIdx.x;
  const int pg = id & 1023;
  const int chunk = (id >> 10) % 24;
  const int h = id / (1024 * 24);     // 0..7 = b*2+br
  const int b = h >> 1, br = h & 1;
  const ushort_t* X = (br ? ybf : xbf) + b * (CCH * HW);
  const float* W = br ? wB : wA;
  const int sidx = br * 256 + b * 64;
  const int pix0 = pg * 4;
  const int r0 = chunk * 8;
  float acc[8][4];
  for (int r = 0; r < 8; r++) for (int p = 0; p < 4; p++) acc[r][p] = 0.f;
  for (int cc = 0; cc < 64; cc++) {
    const float sc = scale[sidx + cc], sh = shift[sidx + cc];
    const u64 raw = *(const u64*)(X + cc * HW + pix0);
    f32x4 xv;
    for (int p = 0; p < 4; p++)
      xv[p] = b2f((ushort_t)(raw >> (16 * p))) * sc + sh;
    for (int r = 0; r < 8; r++) {
      float wv = W[(r0 + r) * 64 + cc];
      for (int p = 0; p < 4; p++) acc[r][p] += wv * xv[p];
    }
  }
  if (chunk < 16) {                    // Q or K rows -> transposed [pix][d]
    ushort_t* dst = chunk < 8 ? Qt : Kt;
    const int d0 = (chunk & 7) * 8;
    for (int p = 0; p < 4; p++) {
      short8 v;
      for (int r = 0; r < 8; r++) v[r] = (short)f2b(acc[r][p]);
      *(short8*)(dst + ((h * HW + pix0 + p) << 6) + d0) = v;
    }
  } else {                             // V rows -> natural [d][pix]
    const int d0 = (chunk - 16) * 8;
    for (int r = 0; r < 8; r++) {
      ushort_t tmp[4];
      for (int p = 0; p < 4; p++) tmp[p] = f2b(acc[r][p]);
      *(u64*)(Vv + (h * CCH + d0 + r) * HW + pix0) = *(const u64*)tmp;
    }
  }
}

// ---------------- flash cross-attention: LDS-staged K/V shared by 8 waves ----------------
// 256 blocks x 512 thr. Block = 1 head x 128 queries (8 waves x 16q), sweeps 64 key-tiles.
// K/V tiles double-buffered in LDS via global_load_lds(16B), counted vmcnt, raw s_barrier.
__global__ void __launch_bounds__(512, 2) k_attn(
    const ushort_t* __restrict__ Qt, const ushort_t* __restrict__ Kt,
    const ushort_t* __restrict__ Vv,
    const float* __restrict__ oAw, const float* __restrict__ oAb,
    const float* __restrict__ oBw, const float* __restrict__ oBb,
    const ushort_t* __restrict__ xbf, const ushort_t* __restrict__ ybf,
    const float* __restrict__ scale, const float* __restrict__ shift,
    float* __restrict__ out) {
  // [0,32768): stage buffers  buf b: K at b*16384, V at b*16384+8192
  // [32768,49152): plds P^T staging, 2KB/wave
  // epilogue: [0,32768) reused as per-wave smO[16][64] f32 (4KB/wave)
  __shared__ __align__(16) char lds[49152];
  const int h = blockIdx.x >> 5;       // 8 heads
  const int qt = blockIdx.x & 31;      // 32 q-tiles of 128
  const int b = h >> 1, br = h & 1;
  const int qh = b * 2 + (1 - br);
  const int tid = threadIdx.x;
  const int lane = tid & 63;
  const int wave = tid >> 6;
  const int q = lane & 15, g = lane >> 4;
  const int qbase = qt * 128 + wave * 16;

  const ushort_t* Qp = Qt + ((qh * HW + qbase + q) << 6);
  const short8 qf0 = *(const short8*)(Qp + g * 8);        // B-frag: Q[d=g*8+j][q]
  const short8 qf1 = *(const short8*)(Qp + 32 + g * 8);

  // staging source (pre-swizzled global addresses; LDS dest is linear: thread t -> t*16 B)
  const ushort_t* Kh = Kt + ((u64)h * HW << 6);
  const ushort_t* Vh = Vv + (u64)h * (CCH * HW);
  const int rr = tid >> 3;                       // tile row 0..63
  const int cc8 = (((tid & 7) ^ (rr & 7)) << 3); // swizzled 16B-chunk, in ushorts
  const ushort_t* gk0 = Kh + (rr << 6) + cc8;    // + kt*4096 per tile
  const ushort_t* gv0 = Vh + rr * HW + cc8;      // + kt*64  per tile
  char* lK = lds + tid * 16;                     // + buf*16384
  char* lV = lds + 8192 + tid * 16;

  float m_run = -1e30f, l_run = 0.f;
  f32x4 o[4] = {};
  char* wp = lds + 32768 + wave * 2048 + (q << 7);
  const int sw = (q & 7) << 4;
  const int fsw = ((q & 7) << 4);                // frag-read swizzle base

  // prologue: stage tile 0 into buf 0
  gload16(gk0, lK);
  gload16(gv0 + 0, lV);

#pragma unroll 1
  for (int it = 0; it < 64; ++it) {
    if (it < 63) {
      const int nb = (it + 1) & 1;
      gload16(gk0 + ((it + 1) << 12), lK + nb * 16384);
      gload16(gv0 + (it + 1) * 64, lV + nb * 16384);
      asm volatile("s_waitcnt vmcnt(2)" ::: "memory");
    } else {
      asm volatile("s_waitcnt vmcnt(0)" ::: "memory");
    }
    __builtin_amdgcn_s_barrier();

    const char* kb = lds + (it & 1) * 16384;
    const char* vb = kb + 8192;
    short8 ka[4][2], va[4][2];
    for (int c = 0; c < 4; c++)
      for (int s = 0; s < 2; s++)
        ka[c][s] = *(const short8*)(kb + (((c * 16 + q) << 7) | (((s * 4 + g) << 4) ^ fsw)));
    for (int cd = 0; cd < 4; cd++)
      for (int s = 0; s < 2; s++)
        va[cd][s] = *(const short8*)(vb + (((cd * 16 + q) << 7) | (((s * 4 + g) << 4) ^ fsw)));

    // S^T[k_local, q] = sum_d K[d,k] Q[d,q]   (swapped operands -> q is lane-local column)
    f32x4 sa[4];
    for (int c = 0; c < 4; c++) {
      f32x4 zz = {0.f, 0.f, 0.f, 0.f};
      zz = __builtin_amdgcn_mfma_f32_16x16x32_bf16(ka[c][0], qf0, zz, 0, 0, 0);
      sa[c] = __builtin_amdgcn_mfma_f32_16x16x32_bf16(ka[c][1], qf1, zz, 0, 0, 0);
    }
    const float sc = 0.125f * 1.44269504f;  // (1/sqrt(C)) * log2(e)
    float z[4][4];
    float mloc = -1e30f;
    for (int c = 0; c < 4; c++)
      for (int i = 0; i < 4; i++) {
        z[c][i] = sa[c][i] * sc;
        mloc = fmaxf(mloc, z[c][i]);
      }
    mloc = fmaxf(mloc, __shfl_xor(mloc, 16));
    mloc = fmaxf(mloc, __shfl_xor(mloc, 32));
    // defer-max (T13): only rescale when tile max grows past m_run + 8
    if (!__all(mloc <= m_run + 8.f)) {
      const float mnew = fmaxf(m_run, mloc);
      const float alpha = exp2f(m_run - mnew);
      l_run *= alpha;
      for (int cd = 0; cd < 4; cd++)
        for (int i = 0; i < 4; i++) o[cd][i] *= alpha;
      m_run = mnew;
    }
    float psum = 0.f;
    u64 pk[4];
    for (int c = 0; c < 4; c++) {
      float p0 = exp2f(z[c][0] - m_run), p1 = exp2f(z[c][1] - m_run);
      float p2 = exp2f(z[c][2] - m_run), p3 = exp2f(z[c][3] - m_run);
      psum += p0 + p1 + p2 + p3;
      pk[c] = (u64)cvtpk(p0, p1) | ((u64)cvtpk(p2, p3) << 32);
    }
    psum += __shfl_xor(psum, 16);
    psum += __shfl_xor(psum, 32);
    l_run += psum;
    // stage P^T (keys c*16+4g+i at column q) into wave-local LDS, XOR-swizzled
    for (int c = 0; c < 4; c++)
      *(u64*)(wp + (((c << 5) | (g << 3)) ^ sw)) = pk[c];
    asm volatile("s_waitcnt lgkmcnt(0)" ::: "memory");
    __builtin_amdgcn_sched_barrier(0);
    const short8 pb0 = *(const short8*)(wp + ((g << 4) ^ sw));
    const short8 pb1 = *(const short8*)(wp + ((64 | (g << 4)) ^ sw));
    for (int cd = 0; cd < 4; cd++) {
      o[cd] = __builtin_amdgcn_mfma_f32_16x16x32_bf16(va[cd][0], pb0, o[cd], 0, 0, 0);
      o[cd] = __builtin_amdgcn_mfma_f32_16x16x32_bf16(va[cd][1], pb1, o[cd], 0, 0, 0);
    }
    __builtin_amdgcn_s_barrier();   // protect buf (it&1) before next prefetch overwrites
  }

  // ---- epilogue: per-wave smO[16q][64d] (reuse stage region), out-proj + residual ----
  __syncthreads();
  float* smW = (float*)(lds + wave * 4096);
  const float inv = 1.f / l_run;
  for (int cd = 0; cd < 4; cd++) {
    f32x4 v;
    for (int i = 0; i < 4; i++) v[i] = o[cd][i] * inv;
    *(f32x4*)(smW + q * 64 + (((cd * 4 + g) ^ q) << 2)) = v;   // 16B-chunk XOR(q&15)
  }
  asm volatile("s_waitcnt lgkmcnt(0)" ::: "memory");
  __builtin_amdgcn_sched_barrier(0);

  const float* W    = br ? oBw : oAw;
  const float* bias = br ? oBb : oAb;
  const ushort_t* xR = (br ? ybf : xbf) + b * (CCH * HW);
  const int sidx = br * 256 + b * 64;
  const int q2 = lane & 15, g2 = lane >> 4;
  const float* smR = (float*)(lds + wave * 4096) + q2 * 64;
  const int pix = qt * 128 + wave * 16 + q2;

  float acc[16];
  for (int oi = 0; oi < 16; oi++) acc[oi] = bias[g2 * 16 + oi];
  for (int c4 = 0; c4 < 16; c4++) {
    const f32x4 Lv = *(const f32x4*)(smR + ((c4 ^ q2) << 2));
    for (int oi = 0; oi < 16; oi++) {
      const f32x4 wv = *(const f32x4*)(W + (g2 * 16 + oi) * 64 + c4 * 4);
      acc[oi] += wv[0] * Lv[0] + wv[1] * Lv[1] + wv[2] * Lv[2] + wv[3] * Lv[3];
    }
  }
  for (int oi = 0; oi < 16; oi++) {
    const int ch = g2 * 16 + oi;
    const float xn = b2f(xR[ch * HW + pix]) * scale[sidx + ch] + shift[sidx + ch];
    out[(b * 128 + br * 64 + ch) * HW + pix] = acc[oi] + xn;
  }
}

extern "C" void kernel_launch(void* const* d_in, const int* in_sizes, int n_in,
                              void* d_out, int out_size, void* d_ws, size_t ws_size,
                              hipStream_t stream) {
  const float* in   = (const float*)d_in[0];
  const float* dw1w = (const float*)d_in[1];
  const float* dw1b = (const float*)d_in[2];
  const float* dw2w = (const float*)d_in[3];
  const float* dw2b = (const float*)d_in[4];
  const float* gnAw = (const float*)d_in[5];
  const float* gnAb = (const float*)d_in[6];
  const float* gnBw = (const float*)d_in[7];
  const float* gnBb = (const float*)d_in[8];
  const float* qAw  = (const float*)d_in[9];
  const float* qBw  = (const float*)d_in[10];
  const float* oAw  = (const float*)d_in[11];
  const float* oAb  = (const float*)d_in[12];
  const float* oBw  = (const float*)d_in[13];
  const float* oBb  = (const float*)d_in[14];
  float* out = (float*)d_out;

  // compact workspace layout: 16 MB + 4 KB
  char* ws = (char*)d_ws;
  ushort_t* xbf = (ushort_t*)ws;             // [4][64][4096] bf16 conv out A
  ushort_t* ybf = xbf + 1048576;             // [4][64][4096] bf16 conv out B
  ushort_t* Qt  = ybf + 1048576;             // [8][4096][64] bf16
  ushort_t* Kt  = Qt + 2097152;              // [8][4096][64] bf16
  ushort_t* Vv  = Kt + 2097152;              // [8][64][4096] bf16
  float* scale  = (float*)(Vv + 2097152);    // [2][4][64]
  float* shift  = scale + 512;               // [2][4][64]

  k_dwconv<<<1024, 256, 0, stream>>>(in, dw1w, dw1b, dw2w, dw2b, xbf, ybf);
  k_stat<<<128, 256, 0, stream>>>(xbf, ybf, gnAw, gnAb, gnBw, gnBb, scale, shift);
  k_qkv<<<768, 256, 0, stream>>>(xbf, ybf, scale, shift, qAw, qBw, Qt, Kt, Vv);
  k_attn<<<256, 512, 0, stream>>>(Qt, Kt, Vv, oAw, oAb, oBw, oBb,
                                  xbf, ybf, scale, shift, out);
}

// Round 8
// 224.720 us; speedup vs baseline: 3.1100x; 1.0157x over previous
//
#include <hip/hip_runtime.h>
#include <hip/hip_bf16.h>

#define HW 4096
#define CCH 64

typedef __attribute__((ext_vector_type(8))) short short8;
typedef __attribute__((ext_vector_type(4))) float f32x4;
typedef unsigned short ushort_t;
typedef unsigned long long u64;

#define SCALE_Q 0.18033688f  // (1/sqrt(64)) * log2(e)

__device__ __forceinline__ unsigned short f2b(float f) {
  unsigned u = __float_as_uint(f);
  return (unsigned short)((u + 0x7fff + ((u >> 16) & 1)) >> 16);  // RNE
}
__device__ __forceinline__ float b2f(ushort_t u) {
  return __uint_as_float(((unsigned)u) << 16);
}
__device__ __forceinline__ unsigned cvtpk(float lo, float hi) {
  unsigned r;
  asm volatile("v_cvt_pk_bf16_f32 %0, %1, %2" : "=v"(r) : "v"(lo), "v"(hi));
  return r;
}
__device__ __forceinline__ void gload16(const void* g, void* l) {
  __builtin_amdgcn_global_load_lds(
      (const __attribute__((address_space(1))) unsigned int*)g,
      (__attribute__((address_space(3))) unsigned int*)l, 16, 0, 0);
}

// ------------- depthwise convs (3x3 pad1 + 5x5 pad2, reflect) + GN partial sums -------------
// 1024 blocks: [bc 0..255][strip 0..3]. Thread: 4 consecutive px; b128 LDS reads.
__global__ void __launch_bounds__(256) k_dwconv(
    const float* __restrict__ in, const float* __restrict__ w1, const float* __restrict__ b1,
    const float* __restrict__ w2, const float* __restrict__ b2,
    ushort_t* __restrict__ x, ushort_t* __restrict__ y, float* __restrict__ sums) {
  __shared__ float sm[20 * 68];
  __shared__ float red[4][4];
  const int bc = blockIdx.x >> 2;
  const int r0 = (blockIdx.x & 3) * 16;
  const int c = bc & 63;
  const float* p = in + bc * HW;
  const int tid = threadIdx.x;
  for (int idx = tid; idx < 20 * 68; idx += 256) {
    int r = r0 + idx / 68 - 2, cc = idx % 68 - 2;
    r = r < 0 ? -r : (r > 63 ? 126 - r : r);
    cc = cc < 0 ? -cc : (cc > 63 ? 126 - cc : cc);
    sm[idx] = p[r * 64 + cc];
  }
  float w1r[9], w2r[25];
  for (int i = 0; i < 9; i++) w1r[i] = w1[c * 9 + i];
  for (int i = 0; i < 25; i++) w2r[i] = w2[c * 25 + i];
  const float bb1 = b1[c], bb2 = b2[c];
  __syncthreads();

  const int i = tid >> 4;            // row 0..15 in strip
  const int j0 = (tid & 15) * 4;     // col
  float rv[5][8];
  for (int u = 0; u < 5; u++) {
    *(f32x4*)&rv[u][0] = *(const f32x4*)&sm[(i + u) * 68 + j0];
    *(f32x4*)&rv[u][4] = *(const f32x4*)&sm[(i + u) * 68 + j0 + 4];
  }
  float a1[4], a2[4];
  for (int px = 0; px < 4; px++) {
    float s2 = bb2;
    for (int u = 0; u < 5; u++)
      for (int v = 0; v < 5; v++) s2 += w2r[u * 5 + v] * rv[u][px + v];
    float s1 = bb1;
    for (int u = 0; u < 3; u++)
      for (int v = 0; v < 3; v++) s1 += w1r[u * 3 + v] * rv[u + 1][px + 1 + v];
    a1[px] = s1 > 0.f ? s1 : 0.01f * s1;
    a2[px] = s2 > 0.f ? s2 : 0.01f * s2;
  }
  ushort_t t1[4], t2[4];
  for (int px = 0; px < 4; px++) { t1[px] = f2b(a1[px]); t2[px] = f2b(a2[px]); }
  const int off = bc * HW + (r0 + i) * 64 + j0;
  *(u64*)(x + off) = *(const u64*)t1;
  *(u64*)(y + off) = *(const u64*)t2;

  // GN partial sums (on f32 pre-round values)
  float s1 = 0, q1 = 0, s2 = 0, q2 = 0;
  for (int px = 0; px < 4; px++) {
    s1 += a1[px]; q1 += a1[px] * a1[px];
    s2 += a2[px]; q2 += a2[px] * a2[px];
  }
  for (int o = 1; o < 64; o <<= 1) {
    s1 += __shfl_xor(s1, o); q1 += __shfl_xor(q1, o);
    s2 += __shfl_xor(s2, o); q2 += __shfl_xor(q2, o);
  }
  if ((tid & 63) == 0) {
    red[tid >> 6][0] = s1; red[tid >> 6][1] = q1;
    red[tid >> 6][2] = s2; red[tid >> 6][3] = q2;
  }
  __syncthreads();
  if (tid == 0) {
    float r4[4];
    for (int k = 0; k < 4; k++)
      r4[k] = red[0][k] + red[1][k] + red[2][k] + red[3][k];
    const int b = bc >> 6, g = (bc & 63) >> 2;
    const int base = b * 32 + g * 2;
    atomicAdd(&sums[base], r4[0]);       atomicAdd(&sums[base + 1], r4[1]);
    atomicAdd(&sums[128 + base], r4[2]); atomicAdd(&sums[128 + base + 1], r4[3]);
  }
}

// -------- qkv projection (GN inline from sums): Qt(pre-scaled),Kt [h][pix][64], V [h][64][pix] --
__global__ void __launch_bounds__(256) k_qkv(
    const ushort_t* __restrict__ xbf, const ushort_t* __restrict__ ybf,
    const float* __restrict__ sums,
    const float* __restrict__ gwA, const float* __restrict__ gbA,
    const float* __restrict__ gwB, const float* __restrict__ gbB,
    const float* __restrict__ wA, const float* __restrict__ wB,
    ushort_t* __restrict__ Qt, ushort_t* __restrict__ Kt, ushort_t* __restrict__ Vv) {
  __shared__ float scs[64], shs[64];
  const int id = blockIdx.x * 256 + threadIdx.x;
  const int pg = id & 1023;
  const int chunk = (id >> 10) % 24;
  const int h = id / (1024 * 24);     // 0..7 = b*2+br
  const int b = h >> 1, br = h & 1;
  if (threadIdx.x < 64) {
    const int ch = threadIdx.x, g = ch >> 2;
    const float s = sums[br * 128 + b * 32 + g * 2];
    const float ss = sums[br * 128 + b * 32 + g * 2 + 1];
    const float mu = s * (1.f / 16384.f);
    const float var = ss * (1.f / 16384.f) - mu * mu;
    const float rsig = rsqrtf(var + 1e-5f);
    const float a = rsig * (br ? gwB : gwA)[ch];
    scs[ch] = a;
    shs[ch] = (br ? gbB : gbA)[ch] - mu * a;
  }
  __syncthreads();
  const ushort_t* X = (br ? ybf : xbf) + b * (CCH * HW);
  const float* W = br ? wB : wA;
  const int pix0 = pg * 4;
  const int r0 = chunk * 8;
  float acc[8][4];
  for (int r = 0; r < 8; r++) for (int p = 0; p < 4; p++) acc[r][p] = 0.f;
  for (int cc = 0; cc < 64; cc++) {
    const float sc = scs[cc], sh = shs[cc];
    const u64 raw = *(const u64*)(X + cc * HW + pix0);
    f32x4 xv;
    for (int p = 0; p < 4; p++)
      xv[p] = b2f((ushort_t)(raw >> (16 * p))) * sc + sh;
    for (int r = 0; r < 8; r++) {
      float wv = W[(r0 + r) * 64 + cc];
      for (int p = 0; p < 4; p++) acc[r][p] += wv * xv[p];
    }
  }
  if (chunk < 16) {                    // Q or K rows -> transposed [pix][d]
    ushort_t* dst = chunk < 8 ? Qt : Kt;
    const float qs = chunk < 8 ? SCALE_Q : 1.0f;   // fold softmax scale into Q
    const int d0 = (chunk & 7) * 8;
    for (int p = 0; p < 4; p++) {
      short8 v;
      for (int r = 0; r < 8; r++) v[r] = (short)f2b(acc[r][p] * qs);
      *(short8*)(dst + ((h * HW + pix0 + p) << 6) + d0) = v;
    }
  } else {                             // V rows -> natural [d][pix]
    const int d0 = (chunk - 16) * 8;
    for (int r = 0; r < 8; r++) {
      ushort_t tmp[4];
      for (int p = 0; p < 4; p++) tmp[p] = f2b(acc[r][p]);
      *(u64*)(Vv + (h * CCH + d0 + r) * HW + pix0) = *(const u64*)tmp;
    }
  }
}

// ---------------- flash cross-attention: KVBLK=128, 2 phases/barrier-pair ----------------
// 512 blocks x 256 thr (4 waves x 16q = 64 q/block), sweeps 32 tiles of 128 keys.
// LDS 72.5KB -> 2 blocks/CU. l via ones-MFMA; Q pre-scaled; defer-max.
__global__ void __launch_bounds__(256, 2) k_attn(
    const ushort_t* __restrict__ Qt, const ushort_t* __restrict__ Kt,
    const ushort_t* __restrict__ Vv,
    const float* __restrict__ oAw, const float* __restrict__ oAb,
    const float* __restrict__ oBw, const float* __restrict__ oBb,
    const ushort_t* __restrict__ xbf, const ushort_t* __restrict__ ybf,
    const float* __restrict__ sums,
    const float* __restrict__ gwA, const float* __restrict__ gbA,
    const float* __restrict__ gwB, const float* __restrict__ gbB,
    float* __restrict__ out) {
  // [0,65536): 2 stage bufs {K 16KB + V 16KB}; [65536,73728): plds 2KB/wave;
  // [73728,74240): GN scale/shift table. Epilogue reuses [0,16K) as per-wave smO.
  __shared__ __align__(16) char lds[74240];
  const int h = blockIdx.x >> 6;       // 8 heads
  const int qt = blockIdx.x & 63;      // 64 q-tiles of 64
  const int b = h >> 1, br = h & 1;
  const int qh = b * 2 + (1 - br);
  const int tid = threadIdx.x;
  const int lane = tid & 63;
  const int wave = tid >> 6;
  const int q = lane & 15, g = lane >> 4;
  const int qbase = qt * 64 + wave * 16;

  float* scs = (float*)(lds + 73728);
  float* shs = scs + 64;
  if (tid < 64) {
    const int ch = tid, gg = ch >> 2;
    const float s = sums[br * 128 + b * 32 + gg * 2];
    const float ss = sums[br * 128 + b * 32 + gg * 2 + 1];
    const float mu = s * (1.f / 16384.f);
    const float var = ss * (1.f / 16384.f) - mu * mu;
    const float rsig = rsqrtf(var + 1e-5f);
    const float a = rsig * (br ? gwB : gwA)[ch];
    scs[ch] = a;
    shs[ch] = (br ? gbB : gbA)[ch] - mu * a;
  }

  const ushort_t* Qp = Qt + ((qh * HW + qbase + q) << 6);
  const short8 qf0 = *(const short8*)(Qp + g * 8);        // B-frag: Qs[d=g*8+j][q]
  const short8 qf1 = *(const short8*)(Qp + 32 + g * 8);

  // staging: K tile [128k][64d] (row 128B), V tile [64d][128k] (row 256B), swizzled source
  const ushort_t* Kh = Kt + ((u64)h * HW << 6);
  const ushort_t* Vh = Vv + (u64)h * (CCH * HW);
  const ushort_t* gk[4];
  const ushort_t* gv[4];
  for (int j = 0; j < 4; j++) {
    const int idx = j * 256 + tid;
    const int rK = idx >> 3, cK = (idx & 7) ^ (rK & 7);
    gk[j] = Kh + (rK << 6) + (cK << 3);                  // + it*8192 per tile
    const int rV = idx >> 4, cV = (idx & 15) ^ (rV & 7);
    gv[j] = Vh + rV * HW + (cV << 3);                    // + it*128 per tile
  }
  char* lK = lds + (tid << 4);
  char* lV = lds + 16384 + (tid << 4);

  float m_run = -1e30f;
  f32x4 o[4] = {};
  f32x4 accl = {};
  char* wp = lds + 65536 + wave * 2048 + (q << 7);
  const int sw = (q & 7) << 4;
  short8 ones;
  for (int j = 0; j < 8; j++) ones[j] = (short)0x3F80;

  // prologue: stage tile 0 into buf 0
  for (int j = 0; j < 4; j++) gload16(gk[j], lK + j * 4096);
  for (int j = 0; j < 4; j++) gload16(gv[j], lV + j * 4096);

#pragma unroll 1
  for (int it = 0; it < 32; ++it) {
    if (it < 31) {
      const int nb = (it + 1) & 1;
      for (int j = 0; j < 4; j++) gload16(gk[j] + (it + 1) * 8192, lK + nb * 32768 + j * 4096);
      for (int j = 0; j < 4; j++) gload16(gv[j] + (it + 1) * 128, lV + nb * 32768 + j * 4096);
      asm volatile("s_waitcnt vmcnt(8)" ::: "memory");
    } else {
      asm volatile("s_waitcnt vmcnt(0)" ::: "memory");
    }
    __builtin_amdgcn_s_barrier();

    const char* kb = lds + (it & 1) * 32768;
    const char* vb = kb + 16384;
#pragma unroll
    for (int ph = 0; ph < 2; ph++) {
      short8 ka[4][2], va[4][2];
      for (int c = 0; c < 4; c++)
        for (int s = 0; s < 2; s++)
          ka[c][s] = *(const short8*)(kb + ((ph * 64 + c * 16 + q) << 7) +
                                      (((s * 4 + g) ^ (q & 7)) << 4));
      for (int cd = 0; cd < 4; cd++)
        for (int s = 0; s < 2; s++)
          va[cd][s] = *(const short8*)(vb + ((cd * 16 + q) << 8) +
                                       (((ph * 8 + s * 4 + g) ^ (q & 7)) << 4));

      // S^T[k,q] (Q pre-scaled -> sa is already log2-domain score)
      f32x4 sa[4];
      for (int c = 0; c < 4; c++) {
        f32x4 zz = {0.f, 0.f, 0.f, 0.f};
        zz = __builtin_amdgcn_mfma_f32_16x16x32_bf16(ka[c][0], qf0, zz, 0, 0, 0);
        sa[c] = __builtin_amdgcn_mfma_f32_16x16x32_bf16(ka[c][1], qf1, zz, 0, 0, 0);
      }
      // wave-local max of 16, then cross-16 reduce
      float m0 = fmaxf(fmaxf(fmaxf(sa[0][0], sa[0][1]), sa[0][2]), sa[0][3]);
      float m1 = fmaxf(fmaxf(fmaxf(sa[1][0], sa[1][1]), sa[1][2]), sa[1][3]);
      float m2 = fmaxf(fmaxf(fmaxf(sa[2][0], sa[2][1]), sa[2][2]), sa[2][3]);
      float m3 = fmaxf(fmaxf(fmaxf(sa[3][0], sa[3][1]), sa[3][2]), sa[3][3]);
      float mloc = fmaxf(fmaxf(m0, m1), fmaxf(m2, m3));
      mloc = fmaxf(mloc, __shfl_xor(mloc, 16));
      mloc = fmaxf(mloc, __shfl_xor(mloc, 32));
      if (!__all(mloc <= m_run + 8.f)) {      // defer-max (T13)
        const float mnew = fmaxf(m_run, mloc);
        const float alpha = exp2f(m_run - mnew);
        for (int cd = 0; cd < 4; cd++)
          for (int i = 0; i < 4; i++) o[cd][i] *= alpha;
        for (int i = 0; i < 4; i++) accl[i] *= alpha;
        m_run = mnew;
      }
      u64 pk[4];
      for (int c = 0; c < 4; c++) {
        float p0 = exp2f(sa[c][0] - m_run), p1 = exp2f(sa[c][1] - m_run);
        float p2 = exp2f(sa[c][2] - m_run), p3 = exp2f(sa[c][3] - m_run);
        pk[c] = (u64)cvtpk(p0, p1) | ((u64)cvtpk(p2, p3) << 32);
      }
      for (int c = 0; c < 4; c++)
        *(u64*)(wp + (((c << 5) | (g << 3)) ^ sw)) = pk[c];
      asm volatile("s_waitcnt lgkmcnt(0)" ::: "memory");
      __builtin_amdgcn_sched_barrier(0);
      const short8 pb0 = *(const short8*)(wp + ((g << 4) ^ sw));
      const short8 pb1 = *(const short8*)(wp + ((64 | (g << 4)) ^ sw));
      for (int cd = 0; cd < 4; cd++) {
        o[cd] = __builtin_amdgcn_mfma_f32_16x16x32_bf16(va[cd][0], pb0, o[cd], 0, 0, 0);
        o[cd] = __builtin_amdgcn_mfma_f32_16x16x32_bf16(va[cd][1], pb1, o[cd], 0, 0, 0);
      }
      // l accumulation on the MFMA pipe (A = ones): accl[i] = sum_k P[k][q]
      accl = __builtin_amdgcn_mfma_f32_16x16x32_bf16(ones, pb0, accl, 0, 0, 0);
      accl = __builtin_amdgcn_mfma_f32_16x16x32_bf16(ones, pb1, accl, 0, 0, 0);
    }
    __builtin_amdgcn_s_barrier();   // all waves done with buf before next prefetch overwrite
  }

  // ---- epilogue: per-wave smO[16q][64d] (reuse stage region), out-proj + residual ----
  __syncthreads();
  float* smW = (float*)(lds + wave * 4096);
  const float inv = 1.f / accl[0];
  for (int cd = 0; cd < 4; cd++) {
    f32x4 v;
    for (int i = 0; i < 4; i++) v[i] = o[cd][i] * inv;
    *(f32x4*)(smW + q * 64 + (((cd * 4 + g) ^ q) << 2)) = v;   // 16B-chunk XOR(q)
  }
  asm volatile("s_waitcnt lgkmcnt(0)" ::: "memory");
  __builtin_amdgcn_sched_barrier(0);

  const float* W    = br ? oBw : oAw;
  const float* bias = br ? oBb : oAb;
  const ushort_t* xR = (br ? ybf : xbf) + b * (CCH * HW);
  const int q2 = lane & 15, g2 = lane >> 4;
  const float* smR = (float*)(lds + wave * 4096) + q2 * 64;
  const int pix = qt * 64 + wave * 16 + q2;

  float acc[16];
  for (int oi = 0; oi < 16; oi++) acc[oi] = bias[g2 * 16 + oi];
  for (int c4 = 0; c4 < 16; c4++) {
    const f32x4 Lv = *(const f32x4*)(smR + ((c4 ^ q2) << 2));
    for (int oi = 0; oi < 16; oi++) {
      const f32x4 wv = *(const f32x4*)(W + (g2 * 16 + oi) * 64 + c4 * 4);
      acc[oi] += wv[0] * Lv[0] + wv[1] * Lv[1] + wv[2] * Lv[2] + wv[3] * Lv[3];
    }
  }
  for (int oi = 0; oi < 16; oi++) {
    const int ch = g2 * 16 + oi;
    const float xn = b2f(xR[ch * HW + pix]) * scs[ch] + shs[ch];
    out[(b * 128 + br * 64 + ch) * HW + pix] = acc[oi] + xn;
  }
}

extern "C" void kernel_launch(void* const* d_in, const int* in_sizes, int n_in,
                              void* d_out, int out_size, void* d_ws, size_t ws_size,
                              hipStream_t stream) {
  const float* in   = (const float*)d_in[0];
  const float* dw1w = (const float*)d_in[1];
  const float* dw1b = (const float*)d_in[2];
  const float* dw2w = (const float*)d_in[3];
  const float* dw2b = (const float*)d_in[4];
  const float* gnAw = (const float*)d_in[5];
  const float* gnAb = (const float*)d_in[6];
  const float* gnBw = (const float*)d_in[7];
  const float* gnBb = (const float*)d_in[8];
  const float* qAw  = (const float*)d_in[9];
  const float* qBw  = (const float*)d_in[10];
  const float* oAw  = (const float*)d_in[11];
  const float* oAb  = (const float*)d_in[12];
  const float* oBw  = (const float*)d_in[13];
  const float* oBb  = (const float*)d_in[14];
  float* out = (float*)d_out;

  // workspace: 16 MB + 1 KB
  char* ws = (char*)d_ws;
  ushort_t* xbf = (ushort_t*)ws;             // [4][64][4096] bf16 conv out A
  ushort_t* ybf = xbf + 1048576;             // [4][64][4096] bf16 conv out B
  ushort_t* Qt  = ybf + 1048576;             // [8][4096][64] bf16 (pre-scaled)
  ushort_t* Kt  = Qt + 2097152;              // [8][4096][64] bf16
  ushort_t* Vv  = Kt + 2097152;              // [8][64][4096] bf16
  float* sums   = (float*)(Vv + 2097152);    // [2][4][16][2] f32

  hipMemsetAsync(sums, 0, 256 * sizeof(float), stream);
  k_dwconv<<<1024, 256, 0, stream>>>(in, dw1w, dw1b, dw2w, dw2b, xbf, ybf, sums);
  k_qkv<<<768, 256, 0, stream>>>(xbf, ybf, sums, gnAw, gnAb, gnBw, gnBb,
                                 qAw, qBw, Qt, Kt, Vv);
  k_attn<<<512, 256, 0, stream>>>(Qt, Kt, Vv, oAw, oAb, oBw, oBb,
                                  xbf, ybf, sums, gnAw, gnAb, gnBw, gnBb, out);
}

// Round 10
// 219.814 us; speedup vs baseline: 3.1794x; 1.0223x over previous
//
#include <hip/hip_runtime.h>
#include <hip/hip_bf16.h>

#define HW 4096
#define CCH 64

typedef __attribute__((ext_vector_type(8))) short short8;
typedef __attribute__((ext_vector_type(4))) float f32x4;
typedef unsigned short ushort_t;
typedef unsigned long long u64;

#define SCALE_Q 0.18033688f  // (1/sqrt(64)) * log2(e)

__device__ __forceinline__ unsigned short f2b(float f) {
  unsigned u = __float_as_uint(f);
  return (unsigned short)((u + 0x7fff + ((u >> 16) & 1)) >> 16);  // RNE
}
__device__ __forceinline__ float b2f(ushort_t u) {
  return __uint_as_float(((unsigned)u) << 16);
}
__device__ __forceinline__ unsigned cvtpk(float lo, float hi) {
  unsigned r;
  asm volatile("v_cvt_pk_bf16_f32 %0, %1, %2" : "=v"(r) : "v"(lo), "v"(hi));
  return r;
}
__device__ __forceinline__ void gload16(const void* g, void* l) {
  __builtin_amdgcn_global_load_lds(
      (const __attribute__((address_space(1))) unsigned int*)g,
      (__attribute__((address_space(3))) unsigned int*)l, 16, 0, 0);
}

// ------------- depthwise convs (3x3 pad1 + 5x5 pad2, reflect) + GN partial slots -------------
// 1024 blocks: [bc 0..255][strip 0..3]. Partials: sums[t*2048 + bc*8 + strip*2 + {0,1}].
__global__ void __launch_bounds__(256) k_dwconv(
    const float* __restrict__ in, const float* __restrict__ w1, const float* __restrict__ b1,
    const float* __restrict__ w2, const float* __restrict__ b2,
    ushort_t* __restrict__ x, ushort_t* __restrict__ y, float* __restrict__ sums) {
  __shared__ float sm[20 * 68];
  __shared__ float red[4][4];
  const int bc = blockIdx.x >> 2;
  const int strip = blockIdx.x & 3;
  const int r0 = strip * 16;
  const int c = bc & 63;
  const float* p = in + bc * HW;
  const int tid = threadIdx.x;
  for (int idx = tid; idx < 20 * 68; idx += 256) {
    int r = r0 + idx / 68 - 2, cc = idx % 68 - 2;
    r = r < 0 ? -r : (r > 63 ? 126 - r : r);
    cc = cc < 0 ? -cc : (cc > 63 ? 126 - cc : cc);
    sm[idx] = p[r * 64 + cc];
  }
  float w1r[9], w2r[25];
  for (int i = 0; i < 9; i++) w1r[i] = w1[c * 9 + i];
  for (int i = 0; i < 25; i++) w2r[i] = w2[c * 25 + i];
  const float bb1 = b1[c], bb2 = b2[c];
  __syncthreads();

  const int i = tid >> 4;            // row 0..15 in strip
  const int j0 = (tid & 15) * 4;     // col
  float rv[5][8];
  for (int u = 0; u < 5; u++) {
    *(f32x4*)&rv[u][0] = *(const f32x4*)&sm[(i + u) * 68 + j0];
    *(f32x4*)&rv[u][4] = *(const f32x4*)&sm[(i + u) * 68 + j0 + 4];
  }
  float a1[4], a2[4];
  for (int px = 0; px < 4; px++) {
    float s2 = bb2;
    for (int u = 0; u < 5; u++)
      for (int v = 0; v < 5; v++) s2 += w2r[u * 5 + v] * rv[u][px + v];
    float s1 = bb1;
    for (int u = 0; u < 3; u++)
      for (int v = 0; v < 3; v++) s1 += w1r[u * 3 + v] * rv[u + 1][px + 1 + v];
    a1[px] = s1 > 0.f ? s1 : 0.01f * s1;
    a2[px] = s2 > 0.f ? s2 : 0.01f * s2;
  }
  ushort_t t1[4], t2[4];
  for (int px = 0; px < 4; px++) { t1[px] = f2b(a1[px]); t2[px] = f2b(a2[px]); }
  const int off = bc * HW + (r0 + i) * 64 + j0;
  *(u64*)(x + off) = *(const u64*)t1;
  *(u64*)(y + off) = *(const u64*)t2;

  // GN partial sums (f32 pre-round values)
  float s1 = 0, q1 = 0, s2 = 0, q2 = 0;
  for (int px = 0; px < 4; px++) {
    s1 += a1[px]; q1 += a1[px] * a1[px];
    s2 += a2[px]; q2 += a2[px] * a2[px];
  }
  for (int o = 1; o < 64; o <<= 1) {
    s1 += __shfl_xor(s1, o); q1 += __shfl_xor(q1, o);
    s2 += __shfl_xor(s2, o); q2 += __shfl_xor(q2, o);
  }
  if ((tid & 63) == 0) {
    red[tid >> 6][0] = s1; red[tid >> 6][1] = q1;
    red[tid >> 6][2] = s2; red[tid >> 6][3] = q2;
  }
  __syncthreads();
  if (tid == 0) {
    float r4[4];
    for (int k = 0; k < 4; k++)
      r4[k] = red[0][k] + red[1][k] + red[2][k] + red[3][k];
    sums[bc * 8 + strip * 2 + 0] = r4[0];
    sums[bc * 8 + strip * 2 + 1] = r4[1];
    sums[2048 + bc * 8 + strip * 2 + 0] = r4[2];
    sums[2048 + bc * 8 + strip * 2 + 1] = r4[3];
  }
}

// GN scale/shift for channel ch (lane ch, 0..63) of branch (b,br): 2 vec loads + 2 shfl.
__device__ __forceinline__ void gn_coeffs(
    const float* __restrict__ sums, int b, int br, int ch,
    const float* __restrict__ gw, const float* __restrict__ gb,
    float& sc_out, float& sh_out) {
  const float* pp = sums + br * 2048 + (b * 64 + ch) * 8;
  const f32x4 pa = *(const f32x4*)pp;
  const f32x4 pb = *(const f32x4*)(pp + 4);
  float s = pa[0] + pa[2] + pb[0] + pb[2];
  float ss = pa[1] + pa[3] + pb[1] + pb[3];
  s += __shfl_xor(s, 1); ss += __shfl_xor(ss, 1);
  s += __shfl_xor(s, 2); ss += __shfl_xor(ss, 2);
  const float mu = s * (1.f / 16384.f);
  const float var = ss * (1.f / 16384.f) - mu * mu;
  const float rsig = rsqrtf(var + 1e-5f);
  const float a = rsig * gw[ch];
  sc_out = a;
  sh_out = gb[ch] - mu * a;
}

// -------- qkv projection (GN inline from partials): Qt(pre-scaled),Kt [h][pix][64], V [h][64][pix]
__global__ void __launch_bounds__(256) k_qkv(
    const ushort_t* __restrict__ xbf, const ushort_t* __restrict__ ybf,
    const float* __restrict__ sums,
    const float* __restrict__ gwA, const float* __restrict__ gbA,
    const float* __restrict__ gwB, const float* __restrict__ gbB,
    const float* __restrict__ wA, const float* __restrict__ wB,
    ushort_t* __restrict__ Qt, ushort_t* __restrict__ Kt, ushort_t* __restrict__ Vv) {
  __shared__ float scs[64], shs[64];
  const int id = blockIdx.x * 256 + threadIdx.x;
  const int pg = id & 1023;
  const int chunk = (id >> 10) % 24;
  const int h = id / (1024 * 24);     // 0..7 = b*2+br (block-uniform)
  const int b = h >> 1, br = h & 1;
  if (threadIdx.x < 64) {
    float a, sh;
    gn_coeffs(sums, b, br, threadIdx.x, br ? gwB : gwA, br ? gbB : gbA, a, sh);
    scs[threadIdx.x] = a;
    shs[threadIdx.x] = sh;
  }
  __syncthreads();
  const ushort_t* X = (br ? ybf : xbf) + b * (CCH * HW);
  const float* W = br ? wB : wA;
  const int pix0 = pg * 4;
  const int r0 = chunk * 8;
  float acc[8][4];
  for (int r = 0; r < 8; r++) for (int p = 0; p < 4; p++) acc[r][p] = 0.f;
  for (int cc = 0; cc < 64; cc++) {
    const float sc = scs[cc], sh = shs[cc];
    const u64 raw = *(const u64*)(X + cc * HW + pix0);
    f32x4 xv;
    for (int p = 0; p < 4; p++)
      xv[p] = b2f((ushort_t)(raw >> (16 * p))) * sc + sh;
    for (int r = 0; r < 8; r++) {
      float wv = W[(r0 + r) * 64 + cc];
      for (int p = 0; p < 4; p++) acc[r][p] += wv * xv[p];
    }
  }
  if (chunk < 16) {                    // Q or K rows -> transposed [pix][d]
    ushort_t* dst = chunk < 8 ? Qt : Kt;
    const float qs = chunk < 8 ? SCALE_Q : 1.0f;   // fold softmax scale into Q
    const int d0 = (chunk & 7) * 8;
    for (int p = 0; p < 4; p++) {
      short8 v;
      for (int r = 0; r < 8; r++) v[r] = (short)f2b(acc[r][p] * qs);
      *(short8*)(dst + ((h * HW + pix0 + p) << 6) + d0) = v;
    }
  } else {                             // V rows -> natural [d][pix]
    const int d0 = (chunk - 16) * 8;
    for (int r = 0; r < 8; r++) {
      ushort_t tmp[4];
      for (int p = 0; p < 4; p++) tmp[p] = f2b(acc[r][p]);
      *(u64*)(Vv + (h * CCH + d0 + r) * HW + pix0) = *(const u64*)tmp;
    }
  }
}

// ---------------- flash cross-attention: KVBLK=64, 3 blocks/CU, fused epilogue ----------------
// 512 blocks x 256 thr (4 waves x 16q = 64 q/block), sweeps 64 tiles of 64 keys.
// LDS 41.5KB -> 3 blocks/CU (12 waves/CU). l via ones-MFMA; Q pre-scaled; defer-max.
__global__ void __launch_bounds__(256, 3) k_attn(
    const ushort_t* __restrict__ Qt, const ushort_t* __restrict__ Kt,
    const ushort_t* __restrict__ Vv,
    const float* __restrict__ oAw, const float* __restrict__ oAb,
    const float* __restrict__ oBw, const float* __restrict__ oBb,
    const ushort_t* __restrict__ xbf, const ushort_t* __restrict__ ybf,
    const float* __restrict__ sums,
    const float* __restrict__ gwA, const float* __restrict__ gbA,
    const float* __restrict__ gwB, const float* __restrict__ gbB,
    float* __restrict__ out) {
  // [0,32768): 2 stage bufs {K 8KB + V 8KB} each; [32768,40960): plds 2KB/wave;
  // [40960,41472): GN scale/shift. Epilogue reuses [0,16K) as per-wave smO.
  __shared__ __align__(16) char lds[41472];
  const int h = blockIdx.x >> 6;       // 8 heads
  const int qt = blockIdx.x & 63;      // 64 q-tiles of 64
  const int b = h >> 1, br = h & 1;
  const int qh = b * 2 + (1 - br);
  const int tid = threadIdx.x;
  const int lane = tid & 63;
  const int wave = tid >> 6;
  const int q = lane & 15, g = lane >> 4;
  const int qbase = qt * 64 + wave * 16;

  float* scs = (float*)(lds + 40960);
  float* shs = scs + 64;
  if (tid < 64) {
    float a, sh;
    gn_coeffs(sums, b, br, tid, br ? gwB : gwA, br ? gbB : gbA, a, sh);
    scs[tid] = a;
    shs[tid] = sh;
  }

  const ushort_t* Qp = Qt + ((qh * HW + qbase + q) << 6);
  const short8 qf0 = *(const short8*)(Qp + g * 8);        // B-frag: Qs[d=g*8+j][q]
  const short8 qf1 = *(const short8*)(Qp + 32 + g * 8);

  // staging: K tile [64k][64d], V tile [64d][64k]; both 128B rows, swizzled source
  const ushort_t* Kh = Kt + ((u64)h * HW << 6);
  const ushort_t* Vh = Vv + (u64)h * (CCH * HW);
  const ushort_t* gk[2];
  const ushort_t* gv[2];
  for (int j = 0; j < 2; j++) {
    const int idx = j * 256 + tid;
    const int rr = idx >> 3, cc = (idx & 7) ^ (rr & 7);
    gk[j] = Kh + (rr << 6) + (cc << 3);                  // + it*4096 per tile
    gv[j] = Vh + rr * HW + (cc << 3);                    // + it*64  per tile
  }
  char* lK = lds + (tid << 4);
  char* lV = lds + 8192 + (tid << 4);

  float m_run = -1e30f;
  f32x4 o[4] = {};
  f32x4 accl = {};
  char* wp = lds + 32768 + wave * 2048 + (q << 7);
  const int sw = (q & 7) << 4;
  short8 ones;
  for (int j = 0; j < 8; j++) ones[j] = (short)0x3F80;

  // prologue: stage tile 0 into buf 0
  for (int j = 0; j < 2; j++) gload16(gk[j], lK + j * 4096);
  for (int j = 0; j < 2; j++) gload16(gv[j], lV + j * 4096);

#pragma unroll 1
  for (int it = 0; it < 64; ++it) {
    if (it < 63) {
      const int nb = (it + 1) & 1;
      for (int j = 0; j < 2; j++)
        gload16(gk[j] + (it + 1) * 4096, lK + nb * 16384 + j * 4096);
      for (int j = 0; j < 2; j++)
        gload16(gv[j] + (it + 1) * 64, lV + nb * 16384 + j * 4096);
      asm volatile("s_waitcnt vmcnt(4)" ::: "memory");
    } else {
      asm volatile("s_waitcnt vmcnt(0)" ::: "memory");
    }
    __builtin_amdgcn_s_barrier();

    const char* kb = lds + (it & 1) * 16384;
    const char* vb = kb + 8192;
    short8 ka[4][2], va[4][2];
    for (int c = 0; c < 4; c++)
      for (int s = 0; s < 2; s++)
        ka[c][s] = *(const short8*)(kb + ((c * 16 + q) << 7) +
                                    (((s * 4 + g) ^ (q & 7)) << 4));
    for (int cd = 0; cd < 4; cd++)
      for (int s = 0; s < 2; s++)
        va[cd][s] = *(const short8*)(vb + ((cd * 16 + q) << 7) +
                                     (((s * 4 + g) ^ (q & 7)) << 4));

    // S^T[k,q] (Q pre-scaled -> log2-domain scores)
    f32x4 sa[4];
    for (int c = 0; c < 4; c++) {
      f32x4 zz = {0.f, 0.f, 0.f, 0.f};
      zz = __builtin_amdgcn_mfma_f32_16x16x32_bf16(ka[c][0], qf0, zz, 0, 0, 0);
      sa[c] = __builtin_amdgcn_mfma_f32_16x16x32_bf16(ka[c][1], qf1, zz, 0, 0, 0);
    }
    float m0 = fmaxf(fmaxf(fmaxf(sa[0][0], sa[0][1]), sa[0][2]), sa[0][3]);
    float m1 = fmaxf(fmaxf(fmaxf(sa[1][0], sa[1][1]), sa[1][2]), sa[1][3]);
    float m2 = fmaxf(fmaxf(fmaxf(sa[2][0], sa[2][1]), sa[2][2]), sa[2][3]);
    float m3 = fmaxf(fmaxf(fmaxf(sa[3][0], sa[3][1]), sa[3][2]), sa[3][3]);
    float mloc = fmaxf(fmaxf(m0, m1), fmaxf(m2, m3));
    mloc = fmaxf(mloc, __shfl_xor(mloc, 16));
    mloc = fmaxf(mloc, __shfl_xor(mloc, 32));
    if (!__all(mloc <= m_run + 8.f)) {      // defer-max (T13)
      const float mnew = fmaxf(m_run, mloc);
      const float alpha = exp2f(m_run - mnew);
      for (int cd = 0; cd < 4; cd++)
        for (int i = 0; i < 4; i++) o[cd][i] *= alpha;
      for (int i = 0; i < 4; i++) accl[i] *= alpha;
      m_run = mnew;
    }
    u64 pk[4];
    for (int c = 0; c < 4; c++) {
      float p0 = exp2f(sa[c][0] - m_run), p1 = exp2f(sa[c][1] - m_run);
      float p2 = exp2f(sa[c][2] - m_run), p3 = exp2f(sa[c][3] - m_run);
      pk[c] = (u64)cvtpk(p0, p1) | ((u64)cvtpk(p2, p3) << 32);
    }
    for (int c = 0; c < 4; c++)
      *(u64*)(wp + (((c << 5) | (g << 3)) ^ sw)) = pk[c];
    asm volatile("s_waitcnt lgkmcnt(0)" ::: "memory");
    __builtin_amdgcn_sched_barrier(0);
    const short8 pb0 = *(const short8*)(wp + ((g << 4) ^ sw));
    const short8 pb1 = *(const short8*)(wp + ((64 | (g << 4)) ^ sw));
    for (int cd = 0; cd < 4; cd++) {
      o[cd] = __builtin_amdgcn_mfma_f32_16x16x32_bf16(va[cd][0], pb0, o[cd], 0, 0, 0);
      o[cd] = __builtin_amdgcn_mfma_f32_16x16x32_bf16(va[cd][1], pb1, o[cd], 0, 0, 0);
    }
    // l on the MFMA pipe: accl[i] = sum_k P[k][q]
    accl = __builtin_amdgcn_mfma_f32_16x16x32_bf16(ones, pb0, accl, 0, 0, 0);
    accl = __builtin_amdgcn_mfma_f32_16x16x32_bf16(ones, pb1, accl, 0, 0, 0);
    __builtin_amdgcn_s_barrier();   // buf reuse protection
  }

  // ---- epilogue: per-wave smO[16q][64d] (reuse stage region), out-proj + residual ----
  __syncthreads();
  float* smW = (float*)(lds + wave * 4096);
  const float inv = 1.f / accl[0];
  for (int cd = 0; cd < 4; cd++) {
    f32x4 v;
    for (int i = 0; i < 4; i++) v[i] = o[cd][i] * inv;
    *(f32x4*)(smW + q * 64 + (((cd * 4 + g) ^ q) << 2)) = v;   // 16B-chunk XOR(q)
  }
  asm volatile("s_waitcnt lgkmcnt(0)" ::: "memory");
  __builtin_amdgcn_sched_barrier(0);

  const float* W    = br ? oBw : oAw;
  const float* bias = br ? oBb : oAb;
  const ushort_t* xR = (br ? ybf : xbf) + b * (CCH * HW);
  const int q2 = lane & 15, g2 = lane >> 4;
  const float* smR = (float*)(lds + wave * 4096) + q2 * 64;
  const int pix = qt * 64 + wave * 16 + q2;

  float acc[16];
  for (int oi = 0; oi < 16; oi++) acc[oi] = bias[g2 * 16 + oi];
  for (int c4 = 0; c4 < 16; c4++) {
    const f32x4 Lv = *(const f32x4*)(smR + ((c4 ^ q2) << 2));
    for (int oi = 0; oi < 16; oi++) {
      const f32x4 wv = *(const f32x4*)(W + (g2 * 16 + oi) * 64 + c4 * 4);
      acc[oi] += wv[0] * Lv[0] + wv[1] * Lv[1] + wv[2] * Lv[2] + wv[3] * Lv[3];
    }
  }
  for (int oi = 0; oi < 16; oi++) {
    const int ch = g2 * 16 + oi;
    const float xn = b2f(xR[ch * HW + pix]) * scs[ch] + shs[ch];
    out[(b * 128 + br * 64 + ch) * HW + pix] = acc[oi] + xn;
  }
}

extern "C" void kernel_launch(void* const* d_in, const int* in_sizes, int n_in,
                              void* d_out, int out_size, void* d_ws, size_t ws_size,
                              hipStream_t stream) {
  const float* in   = (const float*)d_in[0];
  const float* dw1w = (const float*)d_in[1];
  const float* dw1b = (const float*)d_in[2];
  const float* dw2w = (const float*)d_in[3];
  const float* dw2b = (const float*)d_in[4];
  const float* gnAw = (const float*)d_in[5];
  const float* gnAb = (const float*)d_in[6];
  const float* gnBw = (const float*)d_in[7];
  const float* gnBb = (const float*)d_in[8];
  const float* qAw  = (const float*)d_in[9];
  const float* qBw  = (const float*)d_in[10];
  const float* oAw  = (const float*)d_in[11];
  const float* oAb  = (const float*)d_in[12];
  const float* oBw  = (const float*)d_in[13];
  const float* oBb  = (const float*)d_in[14];
  float* out = (float*)d_out;

  // workspace: 16 MB + 16 KB
  char* ws = (char*)d_ws;
  ushort_t* xbf = (ushort_t*)ws;             // [4][64][4096] bf16 conv out A
  ushort_t* ybf = xbf + 1048576;             // [4][64][4096] bf16 conv out B
  ushort_t* Qt  = ybf + 1048576;             // [8][4096][64] bf16 (pre-scaled)
  ushort_t* Kt  = Qt + 2097152;              // [8][4096][64] bf16
  ushort_t* Vv  = Kt + 2097152;              // [8][64][4096] bf16
  float* sums   = (float*)(Vv + 2097152);    // [2][256 bc][4 strip][2] f32 partials

  k_dwconv<<<1024, 256, 0, stream>>>(in, dw1w, dw1b, dw2w, dw2b, xbf, ybf, sums);
  k_qkv<<<768, 256, 0, stream>>>(xbf, ybf, sums, gnAw, gnAb, gnBw, gnBb,
                                 qAw, qBw, Qt, Kt, Vv);
  k_attn<<<512, 256, 0, stream>>>(Qt, Kt, Vv, oAw, oAb, oBw, oBb,
                                  xbf, ybf, sums, gnAw, gnAb, gnBw, gnBb, out);
}